// Round 3
// baseline (903.213 us; speedup 1.0000x reference)
//
#include <hip/hip_runtime.h>
#include <hip/hip_bf16.h>
#include <stdint.h>

// Problem constants (from reference): B=4, S=2048, D=1024, H=16, DK=64
#define S_LEN 2048
#define D_DIM 1024
#define NH    16
#define DKH   64
#define BATCH 4

typedef __bf16 bf16x8 __attribute__((ext_vector_type(8)));
typedef float  f32x4  __attribute__((ext_vector_type(4)));

__device__ __forceinline__ unsigned short f2bf(float x) {
  unsigned u = __float_as_uint(x);
  return (unsigned short)((u + 0x7FFFu + ((u >> 16) & 1u)) >> 16);  // RNE
}
__device__ __forceinline__ float bf2f(unsigned short b) {
  return __uint_as_float(((unsigned)b) << 16);
}

// async global->LDS, 16B per lane. LDS dest is wave-uniform base + lane*16.
__device__ __forceinline__ void gll16(const void* g, void* l) {
  __builtin_amdgcn_global_load_lds((const __attribute__((address_space(1))) unsigned*)g,
                                   (__attribute__((address_space(3))) unsigned*)l, 16, 0, 0);
}

#define MFMA(a, b, c) __builtin_amdgcn_mfma_f32_16x16x32_bf16(a, b, c, 0, 0, 0)

// ---------------------------------------------------------------------------
// Convert fp32 -> bf16 hi/lo, elementwise (for X / inputs), 4 floats/thread
// ---------------------------------------------------------------------------
__global__ void k_split(const float4* __restrict__ x, ushort4* __restrict__ hi,
                        ushort4* __restrict__ lo, int n4) {
  int i = blockIdx.x * 256 + threadIdx.x;
  if (i >= n4) return;
  float4 v = x[i];
  ushort4 h, l;
  h.x = f2bf(v.x); l.x = f2bf(v.x - bf2f(h.x));
  h.y = f2bf(v.y); l.y = f2bf(v.y - bf2f(h.y));
  h.z = f2bf(v.z); l.z = f2bf(v.z - bf2f(h.z));
  h.w = f2bf(v.w); l.w = f2bf(v.w - bf2f(h.w));
  hi[i] = h;
  lo[i] = l;
}

// ---------------------------------------------------------------------------
// Convert + transpose weight: W[K][N] fp32 -> Wt hi/lo [N][K] bf16
// ---------------------------------------------------------------------------
__global__ void k_wt(const float* __restrict__ W, unsigned short* __restrict__ hi,
                     unsigned short* __restrict__ lo) {
  __shared__ float t[64][65];
  const int tid = threadIdx.x;
  const int k0 = blockIdx.x * 64, n0 = blockIdx.y * 64;
#pragma unroll
  for (int i = 0; i < 16; i++) {
    int idx = i * 256 + tid;
    int r = idx >> 6, c = idx & 63;
    t[r][c] = W[(size_t)(k0 + r) * D_DIM + n0 + c];
  }
  __syncthreads();
#pragma unroll
  for (int i = 0; i < 16; i++) {
    int idx = i * 256 + tid;
    int r = idx >> 6, c = idx & 63;
    float v = t[c][r];  // = W[k0+c][n0+r]
    unsigned short h = f2bf(v);
    size_t o = (size_t)(n0 + r) * D_DIM + k0 + c;
    hi[o] = h;
    lo[o] = f2bf(v - bf2f(h));
  }
}

// ---------------------------------------------------------------------------
// hi/lo split GEMM: C[M,N] = A[M,K] * B[K,N], B given transposed as Bt[N][K].
// MODE 0: write C as hi/lo bf16 [M][N] scaled by escale  (Q, K projections)
// MODE 1: write C as hi/lo bf16 transposed per-head Vt[b][h][d][s]  (V proj)
// MODE 2: write C as fp32 [M][N]                         (final O @ Wo)
// ---------------------------------------------------------------------------
template <int MODE>
__global__ __launch_bounds__(256, 2) void gemm_hilo(
    const unsigned short* __restrict__ Ahi, const unsigned short* __restrict__ Alo,
    const unsigned short* __restrict__ Bth, const unsigned short* __restrict__ Btl,
    unsigned short* __restrict__ Chi, unsigned short* __restrict__ Clo,
    float* __restrict__ Cf, float escale) {
  constexpr int N = 1024, K = 1024;
  extern __shared__ char smem[];
  char* sAh = smem;
  char* sAl = smem + 16384;
  char* sBh = smem + 32768;
  char* sBl = smem + 49152;

  const int tid = threadIdx.x;
  const int lane = tid & 63, w = tid >> 6;
  const int wr = w >> 1, wc = w & 1;
  const int m0 = blockIdx.y * 128, n0 = blockIdx.x * 128;

  int gofs[4], lofs[4];
#pragma unroll
  for (int i = 0; i < 4; i++) {
    int c = (w * 4 + i) * 64 + lane;
    int row = c >> 3, s = c & 7;
    int sp = s ^ (row & 7);
    gofs[i] = row * K + sp * 8;
    lofs[i] = (w * 4 + i) * 1024;
  }
  const unsigned short* pAh = Ahi + (size_t)m0 * K;
  const unsigned short* pAl = Alo + (size_t)m0 * K;
  const unsigned short* pBh = Bth + (size_t)n0 * K;
  const unsigned short* pBl = Btl + (size_t)n0 * K;

  f32x4 acc[4][4] = {};

  for (int kt = 0; kt < K / 64; ++kt) {
    const int ko = kt * 64;
#pragma unroll
    for (int i = 0; i < 4; i++) {
      gll16(pAh + ko + gofs[i], sAh + lofs[i]);
      gll16(pAl + ko + gofs[i], sAl + lofs[i]);
      gll16(pBh + ko + gofs[i], sBh + lofs[i]);
      gll16(pBl + ko + gofs[i], sBl + lofs[i]);
    }
    __syncthreads();
#pragma unroll
    for (int kk = 0; kk < 2; kk++) {
      bf16x8 ah[4], al[4], bh[4], bl[4];
      const int cch = kk * 4 + (lane >> 4);
#pragma unroll
      for (int mr = 0; mr < 4; mr++) {
        int row = wr * 64 + mr * 16 + (lane & 15);
        int off = row * 128 + ((cch ^ (row & 7)) << 4);
        ah[mr] = *(const bf16x8*)(sAh + off);
        al[mr] = *(const bf16x8*)(sAl + off);
      }
#pragma unroll
      for (int nr = 0; nr < 4; nr++) {
        int row = wc * 64 + nr * 16 + (lane & 15);
        int off = row * 128 + ((cch ^ (row & 7)) << 4);
        bh[nr] = *(const bf16x8*)(sBh + off);
        bl[nr] = *(const bf16x8*)(sBl + off);
      }
#pragma unroll
      for (int mr = 0; mr < 4; mr++)
#pragma unroll
        for (int nr = 0; nr < 4; nr++) {
          acc[mr][nr] = MFMA(ah[mr], bh[nr], acc[mr][nr]);
          acc[mr][nr] = MFMA(ah[mr], bl[nr], acc[mr][nr]);
          acc[mr][nr] = MFMA(al[mr], bh[nr], acc[mr][nr]);
        }
    }
    __syncthreads();
  }

#pragma unroll
  for (int mr = 0; mr < 4; mr++)
#pragma unroll
    for (int nr = 0; nr < 4; nr++)
#pragma unroll
      for (int j = 0; j < 4; j++) {
        int row = m0 + wr * 64 + mr * 16 + (lane >> 4) * 4 + j;
        int col = n0 + wc * 64 + nr * 16 + (lane & 15);
        float v = acc[mr][nr][j];
        if constexpr (MODE == 0) {
          v *= escale;
          size_t o = (size_t)row * N + col;
          unsigned short h = f2bf(v);
          Chi[o] = h;
          Clo[o] = f2bf(v - bf2f(h));
        } else if constexpr (MODE == 1) {
          int bi = row >> 11, s = row & (S_LEN - 1);
          int hh = col >> 6, d = col & (DKH - 1);
          size_t o = ((size_t)(bi * NH + hh) * DKH + d) * S_LEN + s;
          unsigned short h = f2bf(v);
          Chi[o] = h;
          Clo[o] = f2bf(v - bf2f(h));
        } else {
          Cf[(size_t)row * N + col] = v;
        }
      }
}

// ---------------------------------------------------------------------------
// Flash attention v2: barrier-free (after mask stage), no-max softmax with
// deferred row-sum, K scaled by 1/8 upstream.
// Block = 256 thr = 4 waves; wave owns 32 q rows (2 MFMA row groups).
// K/V fragments loaded DIRECTLY from global (L2-resident), no LDS staging.
// QK^T 3-pass hi/lo; PV 2-pass (P_hi x V_hi + P_hi x V_lo).
// P relayout via per-wave private LDS (XOR-swizzled), no cross-wave sync.
// ---------------------------------------------------------------------------
__global__ void attn2(const unsigned short* __restrict__ Qh, const unsigned short* __restrict__ Ql,
                      const unsigned short* __restrict__ Kh, const unsigned short* __restrict__ Kl,
                      const unsigned short* __restrict__ Vth, const unsigned short* __restrict__ Vtl,
                      const int* __restrict__ mask,
                      unsigned short* __restrict__ Oh, unsigned short* __restrict__ Ol) {
  __shared__ float sBias[S_LEN];
  __shared__ char sP[4][4096];  // per-wave P hi: [32 rows][64 keys] bf16, swizzled

  const int tid = threadIdx.x, lane = tid & 63, w = tid >> 6;
  const int bh = blockIdx.y, b = bh >> 4, h = bh & (NH - 1);
  const int q0 = blockIdx.x * 128 + w * 32;
  const int lo16 = lane & 15, hi4 = lane >> 4;

  for (int i = tid; i < S_LEN; i += 256)
    sBias[i] = mask[b * S_LEN + i] ? 0.f : -1e9f;
  __syncthreads();

  // Q fragments for 2 row-groups x 2 k-chunks (scores pre-scaled via K*0.125)
  bf16x8 qh[2][2], ql[2][2];
#pragma unroll
  for (int g = 0; g < 2; g++)
#pragma unroll
    for (int kk = 0; kk < 2; kk++) {
      size_t base = ((size_t)(b * S_LEN + q0 + g * 16 + lo16)) * D_DIM + h * DKH + kk * 32 + hi4 * 8;
      qh[g][kk] = *(const bf16x8*)(Qh + base);
      ql[g][kk] = *(const bf16x8*)(Ql + base);
    }

  float lsum[2][4] = {};
  f32x4 oacc[2][4] = {};
  char* sPw = sP[w];

  const size_t kbase = (size_t)b * S_LEN * D_DIM + h * DKH + hi4 * 8;
  const size_t vbase = (size_t)bh * DKH * S_LEN;

  for (int sk0 = 0; sk0 < S_LEN; sk0 += 64) {
    // ---- QK^T (3-pass hi/lo), 48 MFMA ----
    f32x4 sc[2][4] = {};
#pragma unroll
    for (int nr = 0; nr < 4; nr++) {
      size_t ka = kbase + (size_t)(sk0 + nr * 16 + lo16) * D_DIM;
      bf16x8 kh0 = *(const bf16x8*)(Kh + ka);
      bf16x8 kh1 = *(const bf16x8*)(Kh + ka + 32);
      bf16x8 kl0 = *(const bf16x8*)(Kl + ka);
      bf16x8 kl1 = *(const bf16x8*)(Kl + ka + 32);
#pragma unroll
      for (int g = 0; g < 2; g++) {
        sc[g][nr] = MFMA(qh[g][0], kh0, sc[g][nr]);
        sc[g][nr] = MFMA(qh[g][1], kh1, sc[g][nr]);
        sc[g][nr] = MFMA(qh[g][0], kl0, sc[g][nr]);
        sc[g][nr] = MFMA(qh[g][1], kl1, sc[g][nr]);
        sc[g][nr] = MFMA(ql[g][0], kh0, sc[g][nr]);
        sc[g][nr] = MFMA(ql[g][1], kh1, sc[g][nr]);
      }
    }
    // ---- exp + deferred sum + P->LDS (hi only) ----
#pragma unroll
    for (int nr = 0; nr < 4; nr++) {
      float bias = sBias[sk0 + nr * 16 + lo16];
#pragma unroll
      for (int g = 0; g < 2; g++)
#pragma unroll
        for (int j = 0; j < 4; j++) {
          float p = __expf(sc[g][nr][j] + bias);
          lsum[g][j] += p;
          int row = g * 16 + hi4 * 4 + j;
          int colb = (nr * 16 + lo16) * 2;
          *(unsigned short*)(sPw + row * 128 + (colb ^ ((row & 7) << 4))) = f2bf(p);
        }
    }
    // ---- P A-fragments (same wave; compiler inserts lgkmcnt) ----
    bf16x8 pa[2][2];
#pragma unroll
    for (int g = 0; g < 2; g++)
#pragma unroll
      for (int kk = 0; kk < 2; kk++) {
        int row = g * 16 + lo16;
        int colb = kk * 64 + hi4 * 16;
        pa[g][kk] = *(const bf16x8*)(sPw + row * 128 + (colb ^ ((row & 7) << 4)));
      }
    // ---- PV (2-pass), 32 MFMA ----
#pragma unroll
    for (int kk = 0; kk < 2; kk++)
#pragma unroll
      for (int f = 0; f < 4; f++) {
        size_t va = vbase + (size_t)(f * 16 + lo16) * S_LEN + sk0 + kk * 32 + hi4 * 8;
        bf16x8 vh = *(const bf16x8*)(Vth + va);
        bf16x8 vl = *(const bf16x8*)(Vtl + va);
#pragma unroll
        for (int g = 0; g < 2; g++) {
          oacc[g][f] = MFMA(pa[g][kk], vh, oacc[g][f]);
          oacc[g][f] = MFMA(pa[g][kk], vl, oacc[g][f]);
        }
      }
  }

  // final row-sum reduce (keys spread over lane&15 within each 16-lane group)
  float inv[2][4];
#pragma unroll
  for (int g = 0; g < 2; g++)
#pragma unroll
    for (int j = 0; j < 4; j++) {
      float s = lsum[g][j];
      s += __shfl_xor(s, 1);
      s += __shfl_xor(s, 2);
      s += __shfl_xor(s, 4);
      s += __shfl_xor(s, 8);
      inv[g][j] = 1.f / s;
    }

#pragma unroll
  for (int g = 0; g < 2; g++)
#pragma unroll
    for (int f = 0; f < 4; f++)
#pragma unroll
      for (int j = 0; j < 4; j++) {
        int row = q0 + g * 16 + hi4 * 4 + j;
        int col = h * DKH + f * 16 + lo16;
        float v = oacc[g][f][j] * inv[g][j];
        size_t o = ((size_t)(b * S_LEN + row)) * D_DIM + col;
        unsigned short hh = f2bf(v);
        Oh[o] = hh;
        Ol[o] = f2bf(v - bf2f(hh));
      }
}

// ---------------------------------------------------------------------------
extern "C" void kernel_launch(void* const* d_in, const int* in_sizes, int n_in,
                              void* d_out, int out_size, void* d_ws, size_t ws_size,
                              hipStream_t stream) {
  const float* X = (const float*)d_in[0];
  const int* mask = (const int*)d_in[1];
  const float* Wq = (const float*)d_in[2];
  const float* Wk = (const float*)d_in[3];
  const float* Wv = (const float*)d_in[4];
  const float* Wo = (const float*)d_in[5];
  float* out = (float*)d_out;

  const size_t MB = 1024 * 1024;
  if (ws_size < 144 * MB) return;  // insufficient scratch -> visible failure

  char* ws = (char*)d_ws;
  unsigned short* Xh = (unsigned short*)(ws);            // 16MB  (later Oh)
  unsigned short* Xl = (unsigned short*)(ws + 16 * MB);  // 16MB  (later Ol)
  unsigned short* Wqth = (unsigned short*)(ws + 32 * MB);
  unsigned short* Wqtl = Wqth + 1024 * 1024;
  unsigned short* Wkth = Wqtl + 1024 * 1024;
  unsigned short* Wktl = Wkth + 1024 * 1024;
  unsigned short* Wvth = Wktl + 1024 * 1024;
  unsigned short* Wvtl = Wvth + 1024 * 1024;
  unsigned short* Woth = Wvtl + 1024 * 1024;
  unsigned short* Wotl = Woth + 1024 * 1024;             // ends at 48MB
  unsigned short* Qh = (unsigned short*)(ws + 48 * MB);
  unsigned short* Ql = (unsigned short*)(ws + 64 * MB);
  unsigned short* Kh = (unsigned short*)(ws + 80 * MB);
  unsigned short* Kl = (unsigned short*)(ws + 96 * MB);
  unsigned short* Vth = (unsigned short*)(ws + 112 * MB);
  unsigned short* Vtl = (unsigned short*)(ws + 128 * MB);

  const int n4 = BATCH * S_LEN * D_DIM / 4;
  k_split<<<(n4 + 255) / 256, 256, 0, stream>>>((const float4*)X, (ushort4*)Xh,
                                                (ushort4*)Xl, n4);
  dim3 wtg(16, 16);
  k_wt<<<wtg, 256, 0, stream>>>(Wq, Wqth, Wqtl);
  k_wt<<<wtg, 256, 0, stream>>>(Wk, Wkth, Wktl);
  k_wt<<<wtg, 256, 0, stream>>>(Wv, Wvth, Wvtl);
  k_wt<<<wtg, 256, 0, stream>>>(Wo, Woth, Wotl);

  dim3 gg(8, 64);  // N/128 x M/128
  gemm_hilo<0><<<gg, 256, 65536, stream>>>(Xh, Xl, Wqth, Wqtl, Qh, Ql, nullptr, 1.0f);
  gemm_hilo<0><<<gg, 256, 65536, stream>>>(Xh, Xl, Wkth, Wktl, Kh, Kl, nullptr, 0.125f);
  gemm_hilo<1><<<gg, 256, 65536, stream>>>(Xh, Xl, Wvth, Wvtl, Vth, Vtl, nullptr, 1.0f);

  dim3 ag(S_LEN / 128, BATCH * NH);  // 16 x 64, 4 waves x 32 q-rows each
  attn2<<<ag, 256, 0, stream>>>(Qh, Ql, Kh, Kl, Vth, Vtl, mask, Xh, Xl);

  gemm_hilo<2><<<gg, 256, 65536, stream>>>(Xh, Xl, Woth, Wotl, nullptr, nullptr, out, 1.0f);
}

// Round 5
// 587.310 us; speedup vs baseline: 1.5379x; 1.5379x over previous
//
#include <hip/hip_runtime.h>
#include <hip/hip_bf16.h>
#include <stdint.h>

// Problem constants (from reference): B=4, S=2048, D=1024, H=16, DK=64
#define S_LEN 2048
#define D_DIM 1024
#define NH    16
#define DKH   64
#define BATCH 4

typedef __bf16 bf16x8 __attribute__((ext_vector_type(8)));
typedef float  f32x4  __attribute__((ext_vector_type(4)));

__device__ __forceinline__ unsigned short f2bf(float x) {
  unsigned u = __float_as_uint(x);
  return (unsigned short)((u + 0x7FFFu + ((u >> 16) & 1u)) >> 16);  // RNE
}
__device__ __forceinline__ float bf2f(unsigned short b) {
  return __uint_as_float(((unsigned)b) << 16);
}

// async global->LDS, 16B per lane. LDS dest is wave-uniform base + lane*16.
__device__ __forceinline__ void gll16(const void* g, void* l) {
  __builtin_amdgcn_global_load_lds((const __attribute__((address_space(1))) unsigned*)g,
                                   (__attribute__((address_space(3))) unsigned*)l, 16, 0, 0);
}

#define MFMA(a, b, c) __builtin_amdgcn_mfma_f32_16x16x32_bf16(a, b, c, 0, 0, 0)

// ---------------------------------------------------------------------------
// Convert fp32 -> bf16 hi/lo, elementwise (for X / inputs), 4 floats/thread
// ---------------------------------------------------------------------------
__global__ void k_split(const float4* __restrict__ x, ushort4* __restrict__ hi,
                        ushort4* __restrict__ lo, int n4) {
  int i = blockIdx.x * 256 + threadIdx.x;
  if (i >= n4) return;
  float4 v = x[i];
  ushort4 h, l;
  h.x = f2bf(v.x); l.x = f2bf(v.x - bf2f(h.x));
  h.y = f2bf(v.y); l.y = f2bf(v.y - bf2f(h.y));
  h.z = f2bf(v.z); l.z = f2bf(v.z - bf2f(h.z));
  h.w = f2bf(v.w); l.w = f2bf(v.w - bf2f(h.w));
  hi[i] = h;
  lo[i] = l;
}

// ---------------------------------------------------------------------------
// Convert + transpose weight: W[K][N] fp32 -> Wt hi/lo [N][K] bf16
// ---------------------------------------------------------------------------
__global__ void k_wt(const float* __restrict__ W, unsigned short* __restrict__ hi,
                     unsigned short* __restrict__ lo) {
  __shared__ float t[64][65];
  const int tid = threadIdx.x;
  const int k0 = blockIdx.x * 64, n0 = blockIdx.y * 64;
#pragma unroll
  for (int i = 0; i < 16; i++) {
    int idx = i * 256 + tid;
    int r = idx >> 6, c = idx & 63;
    t[r][c] = W[(size_t)(k0 + r) * D_DIM + n0 + c];
  }
  __syncthreads();
#pragma unroll
  for (int i = 0; i < 16; i++) {
    int idx = i * 256 + tid;
    int r = idx >> 6, c = idx & 63;
    float v = t[c][r];  // = W[k0+c][n0+r]
    unsigned short h = f2bf(v);
    size_t o = (size_t)(n0 + r) * D_DIM + k0 + c;
    hi[o] = h;
    lo[o] = f2bf(v - bf2f(h));
  }
}

// ---------------------------------------------------------------------------
// hi/lo split GEMM: C[M,N] = A[M,K] * B[K,N], B given transposed as Bt[N][K].
// MODE 0: write C as hi/lo bf16 [M][N] scaled by escale  (Q, K projections)
// MODE 1: write C as hi/lo bf16 transposed per-head Vt[b][h][d][s]  (V proj)
// MODE 2: write C as fp32 [M][N]                         (final O @ Wo)
// ---------------------------------------------------------------------------
template <int MODE>
__global__ __launch_bounds__(256, 2) void gemm_hilo(
    const unsigned short* __restrict__ Ahi, const unsigned short* __restrict__ Alo,
    const unsigned short* __restrict__ Bth, const unsigned short* __restrict__ Btl,
    unsigned short* __restrict__ Chi, unsigned short* __restrict__ Clo,
    float* __restrict__ Cf, float escale) {
  constexpr int N = 1024, K = 1024;
  extern __shared__ char smem[];
  char* sAh = smem;
  char* sAl = smem + 16384;
  char* sBh = smem + 32768;
  char* sBl = smem + 49152;

  const int tid = threadIdx.x;
  const int lane = tid & 63, w = tid >> 6;
  const int wr = w >> 1, wc = w & 1;
  const int m0 = blockIdx.y * 128, n0 = blockIdx.x * 128;

  int gofs[4], lofs[4];
#pragma unroll
  for (int i = 0; i < 4; i++) {
    int c = (w * 4 + i) * 64 + lane;
    int row = c >> 3, s = c & 7;
    int sp = s ^ (row & 7);
    gofs[i] = row * K + sp * 8;
    lofs[i] = (w * 4 + i) * 1024;
  }
  const unsigned short* pAh = Ahi + (size_t)m0 * K;
  const unsigned short* pAl = Alo + (size_t)m0 * K;
  const unsigned short* pBh = Bth + (size_t)n0 * K;
  const unsigned short* pBl = Btl + (size_t)n0 * K;

  f32x4 acc[4][4] = {};

  for (int kt = 0; kt < K / 64; ++kt) {
    const int ko = kt * 64;
#pragma unroll
    for (int i = 0; i < 4; i++) {
      gll16(pAh + ko + gofs[i], sAh + lofs[i]);
      gll16(pAl + ko + gofs[i], sAl + lofs[i]);
      gll16(pBh + ko + gofs[i], sBh + lofs[i]);
      gll16(pBl + ko + gofs[i], sBl + lofs[i]);
    }
    __syncthreads();
#pragma unroll
    for (int kk = 0; kk < 2; kk++) {
      bf16x8 ah[4], al[4], bh[4], bl[4];
      const int cch = kk * 4 + (lane >> 4);
#pragma unroll
      for (int mr = 0; mr < 4; mr++) {
        int row = wr * 64 + mr * 16 + (lane & 15);
        int off = row * 128 + ((cch ^ (row & 7)) << 4);
        ah[mr] = *(const bf16x8*)(sAh + off);
        al[mr] = *(const bf16x8*)(sAl + off);
      }
#pragma unroll
      for (int nr = 0; nr < 4; nr++) {
        int row = wc * 64 + nr * 16 + (lane & 15);
        int off = row * 128 + ((cch ^ (row & 7)) << 4);
        bh[nr] = *(const bf16x8*)(sBh + off);
        bl[nr] = *(const bf16x8*)(sBl + off);
      }
#pragma unroll
      for (int mr = 0; mr < 4; mr++)
#pragma unroll
        for (int nr = 0; nr < 4; nr++) {
          acc[mr][nr] = MFMA(ah[mr], bh[nr], acc[mr][nr]);
          acc[mr][nr] = MFMA(ah[mr], bl[nr], acc[mr][nr]);
          acc[mr][nr] = MFMA(al[mr], bh[nr], acc[mr][nr]);
        }
    }
    __syncthreads();
  }

#pragma unroll
  for (int mr = 0; mr < 4; mr++)
#pragma unroll
    for (int nr = 0; nr < 4; nr++)
#pragma unroll
      for (int j = 0; j < 4; j++) {
        int row = m0 + wr * 64 + mr * 16 + (lane >> 4) * 4 + j;
        int col = n0 + wc * 64 + nr * 16 + (lane & 15);
        float v = acc[mr][nr][j];
        if constexpr (MODE == 0) {
          v *= escale;
          size_t o = (size_t)row * N + col;
          unsigned short h = f2bf(v);
          Chi[o] = h;
          Clo[o] = f2bf(v - bf2f(h));
        } else if constexpr (MODE == 1) {
          int bi = row >> 11, s = row & (S_LEN - 1);
          int hh = col >> 6, d = col & (DKH - 1);
          size_t o = ((size_t)(bi * NH + hh) * DKH + d) * S_LEN + s;
          unsigned short h = f2bf(v);
          Chi[o] = h;
          Clo[o] = f2bf(v - bf2f(h));
        } else {
          Cf[(size_t)row * N + col] = v;
        }
      }
}

// ---------------------------------------------------------------------------
// Flash attention v3: LDS-staged K/V tiles (gll16 + XOR swizzle, 2 barriers)
// + cheap softmax (no max-tracking, deferred row-sum, K pre-scaled by 1/8).
// Block = 256 thr = 4 waves, 128 q rows (wave owns 32). grid.x = (b,h) so
// all q-blocks of one (b,h) land on the same XCD (linear%8 == bh%8).
// QK^T 3-pass hi/lo (48 MFMA/tile/wave); PV 2-pass (32 MFMA/tile/wave).
// P relayout via per-wave private LDS, same-wave lgkmcnt only.
// ---------------------------------------------------------------------------
__global__ __launch_bounds__(256, 3) void attn3(
    const unsigned short* __restrict__ Qh, const unsigned short* __restrict__ Ql,
    const unsigned short* __restrict__ Kh, const unsigned short* __restrict__ Kl,
    const unsigned short* __restrict__ Vth, const unsigned short* __restrict__ Vtl,
    const int* __restrict__ mask,
    unsigned short* __restrict__ Oh, unsigned short* __restrict__ Ol) {
  __shared__ char sKh[8192], sKl[8192], sVh[8192], sVl[8192];  // 64-key tiles
  __shared__ char sP[4][4096];  // per-wave P hi: [32 rows][64 keys] bf16, swizzled

  const int tid = threadIdx.x, lane = tid & 63, w = tid >> 6;
  const int bh = blockIdx.x, b = bh >> 4, h = bh & (NH - 1);
  const int q0 = blockIdx.y * 128 + w * 32;
  const int lo16 = lane & 15, hi4 = lane >> 4;

  // Q fragments for 2 row-groups x 2 k-chunks (scores pre-scaled via K*0.125)
  bf16x8 qh[2][2], ql[2][2];
#pragma unroll
  for (int g = 0; g < 2; g++)
#pragma unroll
    for (int kk = 0; kk < 2; kk++) {
      size_t base = ((size_t)(b * S_LEN + q0 + g * 16 + lo16)) * D_DIM + h * DKH + kk * 32 + hi4 * 8;
      qh[g][kk] = *(const bf16x8*)(Qh + base);
      ql[g][kk] = *(const bf16x8*)(Ql + base);
    }

  // staging offsets: tile rows 0..63 x 8 chunks(16B); LDS slot (row,s) holds
  // global chunk (row, s^(row&7)); dest byte = chunk_id*16 (linear, per-wave)
  int srowK[2], scolK[2], lofs[2];
#pragma unroll
  for (int i = 0; i < 2; i++) {
    int c = (w * 2 + i) * 64 + lane;  // 0..511
    int row = c >> 3, s = c & 7;
    srowK[i] = row;
    scolK[i] = (s ^ (row & 7)) * 8;
    lofs[i] = c * 16 - lane * 16;  // wave-uniform base part
  }

  float lsum[2][4] = {};
  f32x4 oacc[2][4] = {};
  char* sPw = sP[w];

  const size_t kbase = (size_t)b * S_LEN * D_DIM + h * DKH;
  const size_t vbase = (size_t)bh * DKH * S_LEN;
  const int* mrow = mask + b * S_LEN;

  for (int sk0 = 0; sk0 < S_LEN; sk0 += 64) {
    // ---- stage K hi/lo [64 keys][64 dk] and Vt hi/lo [64 d][64 s] ----
#pragma unroll
    for (int i = 0; i < 2; i++) {
      size_t gk = kbase + (size_t)(sk0 + srowK[i]) * D_DIM + scolK[i];
      gll16(Kh + gk, sKh + lofs[i]);
      gll16(Kl + gk, sKl + lofs[i]);
      size_t gv = vbase + (size_t)srowK[i] * S_LEN + sk0 + scolK[i];
      gll16(Vth + gv, sVh + lofs[i]);
      gll16(Vtl + gv, sVl + lofs[i]);
    }
    __syncthreads();

    // ---- QK^T (3-pass hi/lo), 48 MFMA ----
    f32x4 sc[2][4] = {};
#pragma unroll
    for (int nr = 0; nr < 4; nr++) {
      int row = nr * 16 + lo16;
      int off0 = row * 128 + (((0 * 4 + hi4) ^ (row & 7)) << 4);
      int off1 = row * 128 + (((1 * 4 + hi4) ^ (row & 7)) << 4);
      bf16x8 kh0 = *(const bf16x8*)(sKh + off0);
      bf16x8 kh1 = *(const bf16x8*)(sKh + off1);
      bf16x8 kl0 = *(const bf16x8*)(sKl + off0);
      bf16x8 kl1 = *(const bf16x8*)(sKl + off1);
#pragma unroll
      for (int g = 0; g < 2; g++) {
        sc[g][nr] = MFMA(qh[g][0], kh0, sc[g][nr]);
        sc[g][nr] = MFMA(qh[g][1], kh1, sc[g][nr]);
        sc[g][nr] = MFMA(qh[g][0], kl0, sc[g][nr]);
        sc[g][nr] = MFMA(qh[g][1], kl1, sc[g][nr]);
        sc[g][nr] = MFMA(ql[g][0], kh0, sc[g][nr]);
        sc[g][nr] = MFMA(ql[g][1], kh1, sc[g][nr]);
      }
    }

    // ---- exp + deferred sum + P->LDS (hi only) ----
#pragma unroll
    for (int nr = 0; nr < 4; nr++) {
      float bias = mrow[sk0 + nr * 16 + lo16] ? 0.f : -1e9f;
#pragma unroll
      for (int g = 0; g < 2; g++)
#pragma unroll
        for (int j = 0; j < 4; j++) {
          float p = __expf(sc[g][nr][j] + bias);
          lsum[g][j] += p;
          int row = g * 16 + hi4 * 4 + j;
          int colb = (nr * 16 + lo16) * 2;
          *(unsigned short*)(sPw + row * 128 + (colb ^ ((row & 7) << 4))) = f2bf(p);
        }
    }

    // ---- P A-fragments (same wave; compiler inserts lgkmcnt) ----
    bf16x8 pa[2][2];
#pragma unroll
    for (int g = 0; g < 2; g++)
#pragma unroll
      for (int kk = 0; kk < 2; kk++) {
        int row = g * 16 + lo16;
        int colb = kk * 64 + hi4 * 16;
        pa[g][kk] = *(const bf16x8*)(sPw + row * 128 + (colb ^ ((row & 7) << 4)));
      }

    // ---- PV (2-pass), 32 MFMA ----
#pragma unroll
    for (int kk = 0; kk < 2; kk++)
#pragma unroll
      for (int f = 0; f < 4; f++) {
        int vrow = f * 16 + lo16;
        int voff = vrow * 128 + (((kk * 4 + hi4) ^ (vrow & 7)) << 4);
        bf16x8 vh = *(const bf16x8*)(sVh + voff);
        bf16x8 vl = *(const bf16x8*)(sVl + voff);
#pragma unroll
        for (int g = 0; g < 2; g++) {
          oacc[g][f] = MFMA(pa[g][kk], vh, oacc[g][f]);
          oacc[g][f] = MFMA(pa[g][kk], vl, oacc[g][f]);
        }
      }
    __syncthreads();
  }

  // final row-sum reduce (keys spread over lane&15 within each 16-lane group)
  float inv[2][4];
#pragma unroll
  for (int g = 0; g < 2; g++)
#pragma unroll
    for (int j = 0; j < 4; j++) {
      float s = lsum[g][j];
      s += __shfl_xor(s, 1);
      s += __shfl_xor(s, 2);
      s += __shfl_xor(s, 4);
      s += __shfl_xor(s, 8);
      inv[g][j] = 1.f / s;
    }

#pragma unroll
  for (int g = 0; g < 2; g++)
#pragma unroll
    for (int f = 0; f < 4; f++)
#pragma unroll
      for (int j = 0; j < 4; j++) {
        int row = q0 + g * 16 + hi4 * 4 + j;
        int col = h * DKH + f * 16 + lo16;
        float v = oacc[g][f][j] * inv[g][j];
        size_t o = ((size_t)(b * S_LEN + row)) * D_DIM + col;
        unsigned short hh = f2bf(v);
        Oh[o] = hh;
        Ol[o] = f2bf(v - bf2f(hh));
      }
}

// ---------------------------------------------------------------------------
extern "C" void kernel_launch(void* const* d_in, const int* in_sizes, int n_in,
                              void* d_out, int out_size, void* d_ws, size_t ws_size,
                              hipStream_t stream) {
  const float* X = (const float*)d_in[0];
  const int* mask = (const int*)d_in[1];
  const float* Wq = (const float*)d_in[2];
  const float* Wk = (const float*)d_in[3];
  const float* Wv = (const float*)d_in[4];
  const float* Wo = (const float*)d_in[5];
  float* out = (float*)d_out;

  const size_t MB = 1024 * 1024;
  if (ws_size < 144 * MB) return;  // insufficient scratch -> visible failure

  char* ws = (char*)d_ws;
  unsigned short* Xh = (unsigned short*)(ws);            // 16MB  (later Oh)
  unsigned short* Xl = (unsigned short*)(ws + 16 * MB);  // 16MB  (later Ol)
  unsigned short* Wqth = (unsigned short*)(ws + 32 * MB);
  unsigned short* Wqtl = Wqth + 1024 * 1024;
  unsigned short* Wkth = Wqtl + 1024 * 1024;
  unsigned short* Wktl = Wkth + 1024 * 1024;
  unsigned short* Wvth = Wktl + 1024 * 1024;
  unsigned short* Wvtl = Wvth + 1024 * 1024;
  unsigned short* Woth = Wvtl + 1024 * 1024;
  unsigned short* Wotl = Woth + 1024 * 1024;             // ends at 48MB
  unsigned short* Qh = (unsigned short*)(ws + 48 * MB);
  unsigned short* Ql = (unsigned short*)(ws + 64 * MB);
  unsigned short* Kh = (unsigned short*)(ws + 80 * MB);
  unsigned short* Kl = (unsigned short*)(ws + 96 * MB);
  unsigned short* Vth = (unsigned short*)(ws + 112 * MB);
  unsigned short* Vtl = (unsigned short*)(ws + 128 * MB);

  const int n4 = BATCH * S_LEN * D_DIM / 4;
  k_split<<<(n4 + 255) / 256, 256, 0, stream>>>((const float4*)X, (ushort4*)Xh,
                                                (ushort4*)Xl, n4);
  dim3 wtg(16, 16);
  k_wt<<<wtg, 256, 0, stream>>>(Wq, Wqth, Wqtl);
  k_wt<<<wtg, 256, 0, stream>>>(Wk, Wkth, Wktl);
  k_wt<<<wtg, 256, 0, stream>>>(Wv, Wvth, Wvtl);
  k_wt<<<wtg, 256, 0, stream>>>(Wo, Woth, Wotl);

  dim3 gg(8, 64);  // N/128 x M/128
  gemm_hilo<0><<<gg, 256, 65536, stream>>>(Xh, Xl, Wqth, Wqtl, Qh, Ql, nullptr, 1.0f);
  gemm_hilo<0><<<gg, 256, 65536, stream>>>(Xh, Xl, Wkth, Wktl, Kh, Kl, nullptr, 0.125f);
  gemm_hilo<1><<<gg, 256, 65536, stream>>>(Xh, Xl, Wvth, Wvtl, Vth, Vtl, nullptr, 1.0f);

  // grid.x = (b,h): all q-blocks of one (b,h) share linear%8 -> same XCD L2
  dim3 ag(BATCH * NH, S_LEN / 128);  // 64 x 16
  attn3<<<ag, 256, 0, stream>>>(Qh, Ql, Kh, Kl, Vth, Vtl, mask, Xh, Xl);

  gemm_hilo<2><<<gg, 256, 65536, stream>>>(Xh, Xl, Woth, Wotl, nullptr, nullptr, out, 1.0f);
}

// Round 6
// 507.760 us; speedup vs baseline: 1.7788x; 1.1567x over previous
//
#include <hip/hip_runtime.h>
#include <hip/hip_bf16.h>
#include <stdint.h>

// Problem constants (from reference): B=4, S=2048, D=1024, H=16, DK=64
#define S_LEN 2048
#define D_DIM 1024
#define NH    16
#define DKH   64
#define BATCH 4

typedef __bf16 bf16x8 __attribute__((ext_vector_type(8)));
typedef float  f32x4  __attribute__((ext_vector_type(4)));

__device__ __forceinline__ unsigned short f2bf(float x) {
  unsigned u = __float_as_uint(x);
  return (unsigned short)((u + 0x7FFFu + ((u >> 16) & 1u)) >> 16);  // RNE
}
__device__ __forceinline__ float bf2f(unsigned short b) {
  return __uint_as_float(((unsigned)b) << 16);
}

// async global->LDS, 16B per lane. LDS dest is wave-uniform base + lane*16.
__device__ __forceinline__ void gll16(const void* g, void* l) {
  __builtin_amdgcn_global_load_lds((const __attribute__((address_space(1))) unsigned*)g,
                                   (__attribute__((address_space(3))) unsigned*)l, 16, 0, 0);
}

#define MFMA(a, b, c) __builtin_amdgcn_mfma_f32_16x16x32_bf16(a, b, c, 0, 0, 0)

// ---------------------------------------------------------------------------
// Convert fp32 -> bf16 hi/lo, elementwise (for X / inputs), 4 floats/thread
// ---------------------------------------------------------------------------
__global__ void k_split(const float4* __restrict__ x, ushort4* __restrict__ hi,
                        ushort4* __restrict__ lo, int n4) {
  int i = blockIdx.x * 256 + threadIdx.x;
  if (i >= n4) return;
  float4 v = x[i];
  ushort4 h, l;
  h.x = f2bf(v.x); l.x = f2bf(v.x - bf2f(h.x));
  h.y = f2bf(v.y); l.y = f2bf(v.y - bf2f(h.y));
  h.z = f2bf(v.z); l.z = f2bf(v.z - bf2f(h.z));
  h.w = f2bf(v.w); l.w = f2bf(v.w - bf2f(h.w));
  hi[i] = h;
  lo[i] = l;
}

// ---------------------------------------------------------------------------
// Convert + transpose weight: W[K][N] fp32 -> Wt hi/lo [N][K] bf16
// ---------------------------------------------------------------------------
__global__ void k_wt(const float* __restrict__ W, unsigned short* __restrict__ hi,
                     unsigned short* __restrict__ lo) {
  __shared__ float t[64][65];
  const int tid = threadIdx.x;
  const int k0 = blockIdx.x * 64, n0 = blockIdx.y * 64;
#pragma unroll
  for (int i = 0; i < 16; i++) {
    int idx = i * 256 + tid;
    int r = idx >> 6, c = idx & 63;
    t[r][c] = W[(size_t)(k0 + r) * D_DIM + n0 + c];
  }
  __syncthreads();
#pragma unroll
  for (int i = 0; i < 16; i++) {
    int idx = i * 256 + tid;
    int r = idx >> 6, c = idx & 63;
    float v = t[c][r];  // = W[k0+c][n0+r]
    unsigned short h = f2bf(v);
    size_t o = (size_t)(n0 + r) * D_DIM + k0 + c;
    hi[o] = h;
    lo[o] = f2bf(v - bf2f(h));
  }
}

// ---------------------------------------------------------------------------
// hi/lo split GEMM: C[M,N] = A[M,K] * B[K,N], B given transposed as Bt[N][K].
// MODE 0: write C as hi/lo bf16 [M][N] scaled by escale  (Q, K projections)
// MODE 1: write C as hi/lo bf16 transposed per-head Vt[b][h][d][s]  (V proj)
// MODE 2: write C as fp32 [M][N]                         (final O @ Wo)
// ---------------------------------------------------------------------------
template <int MODE>
__global__ __launch_bounds__(256, 2) void gemm_hilo(
    const unsigned short* __restrict__ Ahi, const unsigned short* __restrict__ Alo,
    const unsigned short* __restrict__ Bth, const unsigned short* __restrict__ Btl,
    unsigned short* __restrict__ Chi, unsigned short* __restrict__ Clo,
    float* __restrict__ Cf, float escale) {
  constexpr int N = 1024, K = 1024;
  extern __shared__ char smem[];
  char* sAh = smem;
  char* sAl = smem + 16384;
  char* sBh = smem + 32768;
  char* sBl = smem + 49152;

  const int tid = threadIdx.x;
  const int lane = tid & 63, w = tid >> 6;
  const int wr = w >> 1, wc = w & 1;
  const int m0 = blockIdx.y * 128, n0 = blockIdx.x * 128;

  int gofs[4], lofs[4];
#pragma unroll
  for (int i = 0; i < 4; i++) {
    int c = (w * 4 + i) * 64 + lane;
    int row = c >> 3, s = c & 7;
    int sp = s ^ (row & 7);
    gofs[i] = row * K + sp * 8;
    lofs[i] = (w * 4 + i) * 1024;
  }
  const unsigned short* pAh = Ahi + (size_t)m0 * K;
  const unsigned short* pAl = Alo + (size_t)m0 * K;
  const unsigned short* pBh = Bth + (size_t)n0 * K;
  const unsigned short* pBl = Btl + (size_t)n0 * K;

  f32x4 acc[4][4] = {};

  for (int kt = 0; kt < K / 64; ++kt) {
    const int ko = kt * 64;
#pragma unroll
    for (int i = 0; i < 4; i++) {
      gll16(pAh + ko + gofs[i], sAh + lofs[i]);
      gll16(pAl + ko + gofs[i], sAl + lofs[i]);
      gll16(pBh + ko + gofs[i], sBh + lofs[i]);
      gll16(pBl + ko + gofs[i], sBl + lofs[i]);
    }
    __syncthreads();
#pragma unroll
    for (int kk = 0; kk < 2; kk++) {
      bf16x8 ah[4], al[4], bh[4], bl[4];
      const int cch = kk * 4 + (lane >> 4);
#pragma unroll
      for (int mr = 0; mr < 4; mr++) {
        int row = wr * 64 + mr * 16 + (lane & 15);
        int off = row * 128 + ((cch ^ (row & 7)) << 4);
        ah[mr] = *(const bf16x8*)(sAh + off);
        al[mr] = *(const bf16x8*)(sAl + off);
      }
#pragma unroll
      for (int nr = 0; nr < 4; nr++) {
        int row = wc * 64 + nr * 16 + (lane & 15);
        int off = row * 128 + ((cch ^ (row & 7)) << 4);
        bh[nr] = *(const bf16x8*)(sBh + off);
        bl[nr] = *(const bf16x8*)(sBl + off);
      }
#pragma unroll
      for (int mr = 0; mr < 4; mr++)
#pragma unroll
        for (int nr = 0; nr < 4; nr++) {
          acc[mr][nr] = MFMA(ah[mr], bh[nr], acc[mr][nr]);
          acc[mr][nr] = MFMA(ah[mr], bl[nr], acc[mr][nr]);
          acc[mr][nr] = MFMA(al[mr], bh[nr], acc[mr][nr]);
        }
    }
    __syncthreads();
  }

#pragma unroll
  for (int mr = 0; mr < 4; mr++)
#pragma unroll
    for (int nr = 0; nr < 4; nr++)
#pragma unroll
      for (int j = 0; j < 4; j++) {
        int row = m0 + wr * 64 + mr * 16 + (lane >> 4) * 4 + j;
        int col = n0 + wc * 64 + nr * 16 + (lane & 15);
        float v = acc[mr][nr][j];
        if constexpr (MODE == 0) {
          v *= escale;
          size_t o = (size_t)row * N + col;
          unsigned short h = f2bf(v);
          Chi[o] = h;
          Clo[o] = f2bf(v - bf2f(h));
        } else if constexpr (MODE == 1) {
          int bi = row >> 11, s = row & (S_LEN - 1);
          int hh = col >> 6, d = col & (DKH - 1);
          size_t o = ((size_t)(bi * NH + hh) * DKH + d) * S_LEN + s;
          unsigned short h = f2bf(v);
          Chi[o] = h;
          Clo[o] = f2bf(v - bf2f(h));
        } else {
          Cf[(size_t)row * N + col] = v;
        }
      }
}

// ---------------------------------------------------------------------------
// Flash attention v4: double-buffered K/V prefetch, ONE barrier per tile.
// Two statically distinct LDS buffer sets so the compiler can disambiguate
// gll16(next) from ds_read(cur) and not force a vmcnt drain before compute.
// Cheap softmax (no max-tracking, deferred row-sum, K pre-scaled by 1/8).
// Block = 256 thr = 4 waves, 128 q rows (wave owns 32). grid.x = (b,h) so
// all q-blocks of one (b,h) land on the same XCD (linear%8 == bh%8).
// QK^T 3-pass hi/lo (48 MFMA/tile/wave); PV 2-pass (32 MFMA/tile/wave).
// setprio(1) around MFMA clusters (T5).
// ---------------------------------------------------------------------------
__global__ __launch_bounds__(256, 2) void attn4(
    const unsigned short* __restrict__ Qh, const unsigned short* __restrict__ Ql,
    const unsigned short* __restrict__ Kh, const unsigned short* __restrict__ Kl,
    const unsigned short* __restrict__ Vth, const unsigned short* __restrict__ Vtl,
    const int* __restrict__ mask,
    unsigned short* __restrict__ Oh, unsigned short* __restrict__ Ol) {
  // buffer set 0
  __shared__ char sKh0[8192], sKl0[8192], sVh0[8192], sVl0[8192];
  // buffer set 1
  __shared__ char sKh1[8192], sKl1[8192], sVh1[8192], sVl1[8192];
  __shared__ char sP[4][4096];  // per-wave P hi: [32 rows][64 keys] bf16, swizzled

  const int tid = threadIdx.x, lane = tid & 63, w = tid >> 6;
  const int bh = blockIdx.x, b = bh >> 4, h = bh & (NH - 1);
  const int q0 = blockIdx.y * 128 + w * 32;
  const int lo16 = lane & 15, hi4 = lane >> 4;

  // Q fragments for 2 row-groups x 2 k-chunks (scores pre-scaled via K*0.125)
  bf16x8 qh[2][2], ql[2][2];
#pragma unroll
  for (int g = 0; g < 2; g++)
#pragma unroll
    for (int kk = 0; kk < 2; kk++) {
      size_t base = ((size_t)(b * S_LEN + q0 + g * 16 + lo16)) * D_DIM + h * DKH + kk * 32 + hi4 * 8;
      qh[g][kk] = *(const bf16x8*)(Qh + base);
      ql[g][kk] = *(const bf16x8*)(Ql + base);
    }

  // staging offsets: tile rows 0..63 x 8 chunks(16B); LDS slot (row,s) holds
  // global chunk (row, s^(row&7)); dest byte = chunk_id*16 (linear, per-wave)
  int srowK[2], scolK[2], lofs[2];
#pragma unroll
  for (int i = 0; i < 2; i++) {
    int c = (w * 2 + i) * 64 + lane;  // 0..511
    int row = c >> 3, s = c & 7;
    srowK[i] = row;
    scolK[i] = (s ^ (row & 7)) * 8;
    lofs[i] = c * 16 - lane * 16;  // wave-uniform base part
  }

  float lsum[2][4] = {};
  f32x4 oacc[2][4] = {};
  char* sPw = sP[w];

  const size_t kbase = (size_t)b * S_LEN * D_DIM + h * DKH;
  const size_t vbase = (size_t)bh * DKH * S_LEN;
  const int* mrow = mask + b * S_LEN;

  // stage K/V tile for key-block starting at sk0 into the given buffer set
  auto STAGE = [&](char* dKh, char* dKl, char* dVh, char* dVl, int sk0) {
#pragma unroll
    for (int i = 0; i < 2; i++) {
      size_t gk = kbase + (size_t)(sk0 + srowK[i]) * D_DIM + scolK[i];
      gll16(Kh + gk, dKh + lofs[i]);
      gll16(Kl + gk, dKl + lofs[i]);
      size_t gv = vbase + (size_t)srowK[i] * S_LEN + sk0 + scolK[i];
      gll16(Vth + gv, dVh + lofs[i]);
      gll16(Vtl + gv, dVl + lofs[i]);
    }
  };

  // compute one 64-key tile from the given buffer set
  auto COMPUTE = [&](const char* cKh, const char* cKl, const char* cVh,
                     const char* cVl, int sk0) {
    // ---- QK^T (3-pass hi/lo), 48 MFMA ----
    f32x4 sc[2][4] = {};
    __builtin_amdgcn_s_setprio(1);
#pragma unroll
    for (int nr = 0; nr < 4; nr++) {
      int row = nr * 16 + lo16;
      int off0 = row * 128 + ((hi4 ^ (row & 7)) << 4);
      int off1 = row * 128 + (((4 + hi4) ^ (row & 7)) << 4);
      bf16x8 kh0 = *(const bf16x8*)(cKh + off0);
      bf16x8 kh1 = *(const bf16x8*)(cKh + off1);
      bf16x8 kl0 = *(const bf16x8*)(cKl + off0);
      bf16x8 kl1 = *(const bf16x8*)(cKl + off1);
#pragma unroll
      for (int g = 0; g < 2; g++) {
        sc[g][nr] = MFMA(qh[g][0], kh0, sc[g][nr]);
        sc[g][nr] = MFMA(qh[g][1], kh1, sc[g][nr]);
        sc[g][nr] = MFMA(qh[g][0], kl0, sc[g][nr]);
        sc[g][nr] = MFMA(qh[g][1], kl1, sc[g][nr]);
        sc[g][nr] = MFMA(ql[g][0], kh0, sc[g][nr]);
        sc[g][nr] = MFMA(ql[g][1], kh1, sc[g][nr]);
      }
    }
    __builtin_amdgcn_s_setprio(0);

    // ---- exp + deferred sum + P->LDS (hi only) ----
#pragma unroll
    for (int nr = 0; nr < 4; nr++) {
      float bias = mrow[sk0 + nr * 16 + lo16] ? 0.f : -1e9f;
#pragma unroll
      for (int g = 0; g < 2; g++)
#pragma unroll
        for (int j = 0; j < 4; j++) {
          float p = __expf(sc[g][nr][j] + bias);
          lsum[g][j] += p;
          int row = g * 16 + hi4 * 4 + j;
          int colb = (nr * 16 + lo16) * 2;
          *(unsigned short*)(sPw + row * 128 + (colb ^ ((row & 7) << 4))) = f2bf(p);
        }
    }

    // ---- P A-fragments (same wave; compiler inserts lgkmcnt) ----
    bf16x8 pa[2][2];
#pragma unroll
    for (int g = 0; g < 2; g++)
#pragma unroll
      for (int kk = 0; kk < 2; kk++) {
        int row = g * 16 + lo16;
        int colb = kk * 64 + hi4 * 16;
        pa[g][kk] = *(const bf16x8*)(sPw + row * 128 + (colb ^ ((row & 7) << 4)));
      }

    // ---- PV (2-pass), 32 MFMA ----
    __builtin_amdgcn_s_setprio(1);
#pragma unroll
    for (int kk = 0; kk < 2; kk++)
#pragma unroll
      for (int f = 0; f < 4; f++) {
        int vrow = f * 16 + lo16;
        int voff = vrow * 128 + (((kk * 4 + hi4) ^ (vrow & 7)) << 4);
        bf16x8 vh = *(const bf16x8*)(cVh + voff);
        bf16x8 vl = *(const bf16x8*)(cVl + voff);
#pragma unroll
        for (int g = 0; g < 2; g++) {
          oacc[g][f] = MFMA(pa[g][kk], vh, oacc[g][f]);
          oacc[g][f] = MFMA(pa[g][kk], vl, oacc[g][f]);
        }
      }
    __builtin_amdgcn_s_setprio(0);
  };

  // prologue: stage tile 0 into set 0
  STAGE(sKh0, sKl0, sVh0, sVl0, 0);
  __syncthreads();

  // main loop: 32 tiles, unrolled x2 so buffer identity is compile-time
  for (int kt = 0; kt < S_LEN / 64; kt += 2) {
    const int sk0 = kt * 64;
    // even tile: compute set0, prefetch tile kt+1 into set1
    STAGE(sKh1, sKl1, sVh1, sVl1, sk0 + 64);
    COMPUTE(sKh0, sKl0, sVh0, sVl0, sk0);
    __syncthreads();
    // odd tile: compute set1, prefetch tile kt+2 into set0
    if (kt + 2 < S_LEN / 64) STAGE(sKh0, sKl0, sVh0, sVl0, sk0 + 128);
    COMPUTE(sKh1, sKl1, sVh1, sVl1, sk0 + 64);
    __syncthreads();
  }

  // final row-sum reduce (keys spread over lane&15 within each 16-lane group)
  float inv[2][4];
#pragma unroll
  for (int g = 0; g < 2; g++)
#pragma unroll
    for (int j = 0; j < 4; j++) {
      float s = lsum[g][j];
      s += __shfl_xor(s, 1);
      s += __shfl_xor(s, 2);
      s += __shfl_xor(s, 4);
      s += __shfl_xor(s, 8);
      inv[g][j] = 1.f / s;
    }

#pragma unroll
  for (int g = 0; g < 2; g++)
#pragma unroll
    for (int f = 0; f < 4; f++)
#pragma unroll
      for (int j = 0; j < 4; j++) {
        int row = q0 + g * 16 + hi4 * 4 + j;
        int col = h * DKH + f * 16 + lo16;
        float v = oacc[g][f][j] * inv[g][j];
        size_t o = ((size_t)(b * S_LEN + row)) * D_DIM + col;
        unsigned short hh = f2bf(v);
        Oh[o] = hh;
        Ol[o] = f2bf(v - bf2f(hh));
      }
}

// ---------------------------------------------------------------------------
extern "C" void kernel_launch(void* const* d_in, const int* in_sizes, int n_in,
                              void* d_out, int out_size, void* d_ws, size_t ws_size,
                              hipStream_t stream) {
  const float* X = (const float*)d_in[0];
  const int* mask = (const int*)d_in[1];
  const float* Wq = (const float*)d_in[2];
  const float* Wk = (const float*)d_in[3];
  const float* Wv = (const float*)d_in[4];
  const float* Wo = (const float*)d_in[5];
  float* out = (float*)d_out;

  const size_t MB = 1024 * 1024;
  if (ws_size < 144 * MB) return;  // insufficient scratch -> visible failure

  char* ws = (char*)d_ws;
  unsigned short* Xh = (unsigned short*)(ws);            // 16MB  (later Oh)
  unsigned short* Xl = (unsigned short*)(ws + 16 * MB);  // 16MB  (later Ol)
  unsigned short* Wqth = (unsigned short*)(ws + 32 * MB);
  unsigned short* Wqtl = Wqth + 1024 * 1024;
  unsigned short* Wkth = Wqtl + 1024 * 1024;
  unsigned short* Wktl = Wkth + 1024 * 1024;
  unsigned short* Wvth = Wktl + 1024 * 1024;
  unsigned short* Wvtl = Wvth + 1024 * 1024;
  unsigned short* Woth = Wvtl + 1024 * 1024;
  unsigned short* Wotl = Woth + 1024 * 1024;             // ends at 48MB
  unsigned short* Qh = (unsigned short*)(ws + 48 * MB);
  unsigned short* Ql = (unsigned short*)(ws + 64 * MB);
  unsigned short* Kh = (unsigned short*)(ws + 80 * MB);
  unsigned short* Kl = (unsigned short*)(ws + 96 * MB);
  unsigned short* Vth = (unsigned short*)(ws + 112 * MB);
  unsigned short* Vtl = (unsigned short*)(ws + 128 * MB);

  const int n4 = BATCH * S_LEN * D_DIM / 4;
  k_split<<<(n4 + 255) / 256, 256, 0, stream>>>((const float4*)X, (ushort4*)Xh,
                                                (ushort4*)Xl, n4);
  dim3 wtg(16, 16);
  k_wt<<<wtg, 256, 0, stream>>>(Wq, Wqth, Wqtl);
  k_wt<<<wtg, 256, 0, stream>>>(Wk, Wkth, Wktl);
  k_wt<<<wtg, 256, 0, stream>>>(Wv, Wvth, Wvtl);
  k_wt<<<wtg, 256, 0, stream>>>(Wo, Woth, Wotl);

  dim3 gg(8, 64);  // N/128 x M/128
  gemm_hilo<0><<<gg, 256, 65536, stream>>>(Xh, Xl, Wqth, Wqtl, Qh, Ql, nullptr, 1.0f);
  gemm_hilo<0><<<gg, 256, 65536, stream>>>(Xh, Xl, Wkth, Wktl, Kh, Kl, nullptr, 0.125f);
  gemm_hilo<1><<<gg, 256, 65536, stream>>>(Xh, Xl, Wvth, Wvtl, Vth, Vtl, nullptr, 1.0f);

  // grid.x = (b,h): all q-blocks of one (b,h) share linear%8 -> same XCD L2
  dim3 ag(BATCH * NH, S_LEN / 128);  // 64 x 16
  attn4<<<ag, 256, 0, stream>>>(Qh, Ql, Kh, Kl, Vth, Vtl, mask, Xh, Xl);

  gemm_hilo<2><<<gg, 256, 65536, stream>>>(Xh, Xl, Woth, Wotl, nullptr, nullptr, out, 1.0f);
}